// Round 2
// baseline (137.019 us; speedup 1.0000x reference)
//
#include <hip/hip_runtime.h>
#include <math.h>

// Problem constants
#define N_LEN 16384
#define NMODES 64
#define NROWS 1024          // B*C = 32*32
#define PAD 72              // LDS row pitch in bf16 elems (144 B, 16B-aligned)
#define REV_SCALE 6.103515625e-05f   // 1/16384 (exact)
#define SPLIT 64            // split-K chunks for gemm1

typedef __bf16  bf16x8  __attribute__((ext_vector_type(8)));
typedef float   floatx16 __attribute__((ext_vector_type(16)));

// fp32 -> bf16 round-to-nearest-even (header-independent)
__device__ inline unsigned short f2b(float f) {
    unsigned u = __float_as_uint(f);
    u += 0x7fffu + ((u >> 16) & 1u);
    return (unsigned short)(u >> 16);
}

// cas(2*pi*k/N) rounded to bf16, k in [0, N).  v_sin/v_cos take REVOLUTIONS,
// so the argument needs no range reduction beyond the caller's "& 16383".
__device__ inline unsigned short cas_bf16(unsigned k) {
    float rev = (float)k * REV_SCALE;
#if __has_builtin(__builtin_amdgcn_sinf) && __has_builtin(__builtin_amdgcn_cosf)
    float s = __builtin_amdgcn_sinf(rev);
    float c = __builtin_amdgcn_cosf(rev);
#else
    float s, c;
    sincosf(rev * 6.28318530717958647692f, &s, &c);
#endif
    return f2b(c + s);
}

// ---------------------------------------------------------------------------
// GEMM1: xm[row][mode] += sum_{n in chunk s} x[row][n] * cas(2pi n m/N)
// MFMA 32x32x16 bf16. Block: 64 rows x 64 modes, 4 waves:
// wave w -> (row-tile wr = w&1, mode-tile wm = w>>1), one acc[16] each.
// Grid (16, SPLIT) = 1024 blocks = 4/CU (2x the old TLP at 18.4 KB LDS).
// Per 64-n sub-tile: stage x (fp32->bf16, reg double-buffered) + GENERATE
// the 64x64 cas tile in LDS (16 cas/thread, v_sin/v_cos — no global table).
// Epilogue: device-scope fp32 atomicAdd into XM (replaces partials+reduce).
// A frag: xs[wr*32+(lane&31)][ks*16+(lane>>5)*8]  (16B contiguous)
// B frag: ts[wm*32+(lane&31)][ks*16+(lane>>5)*8]
// D: col(mode)=lane&31, row=(r&3)+8*(r>>2)+4*(lane>>5)   [m74/m101]
// ---------------------------------------------------------------------------
#define G1_RB 64

__global__ __launch_bounds__(256) void gemm1(const float* __restrict__ x,
                                             float* __restrict__ xm,
                                             int ntiles) {
    __shared__ unsigned short xs[G1_RB * PAD];   // 9.2 KB
    __shared__ unsigned short ts[64 * PAD];      // 9.2 KB
    const int tid  = threadIdx.x;
    const int lane = tid & 63;
    const int w    = tid >> 6;
    const int q    = lane >> 5;
    const int m    = lane & 31;
    const int wr   = w & 1;
    const int wm   = w >> 1;
    const int row0 = blockIdx.x * G1_RB;
    const int n0   = blockIdx.y * (ntiles * 64);

    // table-gen ownership: this thread fills ts[mrow][nl0 .. nl0+16)
    const int mrow = tid >> 2;
    const int nl0  = (tid & 3) * 16;

    floatx16 acc;
#pragma unroll
    for (int i = 0; i < 16; ++i) acc[i] = 0.f;

    float4 xr[4];
    // prologue: load x sub-tile 0 into regs (64 rows x 64 cols fp32)
    {
        const int base = n0;
#pragma unroll
        for (int it = 0; it < 4; ++it) {
            int cid = it * 256 + tid, rr = cid >> 4, cc = (cid & 15) * 4;
            xr[it] = *(const float4*)(x + (size_t)(row0 + rr) * N_LEN + base + cc);
        }
    }

    for (int t = 0; t < ntiles; ++t) {
        __syncthreads();   // previous compute done before LDS overwrite
        // x regs -> LDS (fp32 -> bf16)
#pragma unroll
        for (int it = 0; it < 4; ++it) {
            int cid = it * 256 + tid, rr = cid >> 4, cc = (cid & 15) * 4;
            ushort4 v;
            v.x = f2b(xr[it].x); v.y = f2b(xr[it].y);
            v.z = f2b(xr[it].z); v.w = f2b(xr[it].w);
            *(ushort4*)(xs + rr * PAD + cc) = v;
        }
        // prefetch next x sub-tile (loads stay in flight during table-gen)
        if (t + 1 < ntiles) {
            const int base = n0 + (t + 1) * 64;
#pragma unroll
            for (int it = 0; it < 4; ++it) {
                int cid = it * 256 + tid, rr = cid >> 4, cc = (cid & 15) * 4;
                xr[it] = *(const float4*)(x + (size_t)(row0 + rr) * N_LEN + base + cc);
            }
        }
        // generate cas tile: ts[mrow][nl] = cas(mrow * (n0 + t*64 + nl))
        {
            unsigned nb = (unsigned)(n0 + t * 64 + nl0);
            unsigned k  = ((unsigned)mrow * nb) & (N_LEN - 1);
            unsigned pk[8];
#pragma unroll
            for (int j = 0; j < 8; ++j) {
                unsigned lo = cas_bf16(k); k = (k + mrow) & (N_LEN - 1);
                unsigned hi = cas_bf16(k); k = (k + mrow) & (N_LEN - 1);
                pk[j] = lo | (hi << 16);
            }
            uint4* dst = (uint4*)(ts + mrow * PAD + nl0);
            dst[0] = make_uint4(pk[0], pk[1], pk[2], pk[3]);
            dst[1] = make_uint4(pk[4], pk[5], pk[6], pk[7]);
        }
        __syncthreads();
#pragma unroll
        for (int ks = 0; ks < 4; ++ks) {
            bf16x8 a = *(const bf16x8*)(xs + (wr * 32 + m) * PAD + ks * 16 + q * 8);
            bf16x8 b = *(const bf16x8*)(ts + (wm * 32 + m) * PAD + ks * 16 + q * 8);
            acc = __builtin_amdgcn_mfma_f32_32x32x16_bf16(a, b, acc, 0, 0, 0);
        }
    }

    // accumulate into xm (device-scope atomics; XM pre-zeroed by memset node)
    float* pb = xm + (size_t)(row0 + wr * 32) * NMODES + wm * 32;
#pragma unroll
    for (int r = 0; r < 16; ++r) {
        int rowt = (r & 3) + 8 * (r >> 2) + 4 * q;
        atomicAdd(pb + rowt * NMODES + m, acc[r]);
    }
}

// ---------------------------------------------------------------------------
// Mix: z[b][o][k] = (1/N) * sin(pw[0][o][k]) *
//      sum_i xm[b][i][k]*ye + xm[b][i][kf]*yo,  kf=(64-k)&63.  Output bf16.
// ---------------------------------------------------------------------------
__global__ __launch_bounds__(256) void mixk(const float* __restrict__ xm,
                                            const float* __restrict__ w1,
                                            const float* __restrict__ pw,
                                            unsigned short* __restrict__ zb) {
    int k = threadIdx.x & 63;
    int wave = threadIdx.x >> 6;
    int b = blockIdx.x;
    int o = blockIdx.y * 4 + wave;
    int kf = (NMODES - k) & 63;

    float acc = 0.f;
#pragma unroll 4
    for (int i = 0; i < 32; ++i) {
        float xv  = xm[(size_t)(b * 32 + i) * NMODES + k];
        float xvf = xm[(size_t)(b * 32 + i) * NMODES + kf];
        float w   = w1[(size_t)(i * 32 + o) * NMODES + k];
        float wf  = w1[(size_t)(i * 32 + o) * NMODES + kf];
        acc = fmaf(xv, 0.5f * (w + wf), acc);
        acc = fmaf(xvf, 0.5f * (w - wf), acc);
    }
    const float sc = 1.0f / (float)N_LEN;
    zb[(size_t)(b * 32 + o) * NMODES + k] =
        f2b(acc * sinf(pw[(size_t)o * NMODES + k]) * sc);
}

// ---------------------------------------------------------------------------
// GEMM2: out[row][n] = sum_m z[row][m] * cas(2pi n m/N)   (1/N already in z)
// MFMA 32x32x16 bf16, K=64 = 4 k-steps. Block: 64 rows x 256 n, 4 waves
// (wave w: rows (w&1)*32..+32, n (w>>1)*128..+128 = 4 N-tiles).
// The 256x64 cas tile is GENERATED in LDS (thread tid owns row n=nb0+tid,
// 64 modes, incremental k += n — no global table). z tile staged from global.
// Store fp32 dwords (2 x 128B segments per store inst). Grid (16, 64).
// ---------------------------------------------------------------------------
#define G2_NB 256

__global__ __launch_bounds__(256) void gemm2(const unsigned short* __restrict__ zb,
                                             float* __restrict__ out) {
    __shared__ unsigned short tts[G2_NB * PAD];  // 36.9 KB
    __shared__ unsigned short zs[64 * PAD];      //  9.2 KB
    const int tid  = threadIdx.x;
    const int lane = tid & 63;
    const int w    = tid >> 6;
    const int q    = lane >> 5;
    const int m    = lane & 31;
    const int wr   = w & 1;
    const int wn   = w >> 1;
    const int row0 = blockIdx.x * 64;
    const int nb0  = blockIdx.y * G2_NB;

    // stage z tile first (global loads in flight during table-gen VALU)
    uint4 zr[2];
#pragma unroll
    for (int it = 0; it < 2; ++it) {
        int idx = it * 256 + tid, rr = idx >> 3, c = idx & 7;
        zr[it] = *(const uint4*)(zb + (size_t)(row0 + rr) * NMODES + c * 8);
    }

    // generate cas tile: tts[tid][mm] = cas((nb0+tid) * mm), mm = 0..63
    {
        unsigned n = (unsigned)(nb0 + tid);
        unsigned k = 0;
        uint4* dst = (uint4*)(tts + tid * PAD);
#pragma unroll
        for (int g = 0; g < 8; ++g) {
            unsigned pk[4];
#pragma unroll
            for (int j = 0; j < 4; ++j) {
                unsigned lo = cas_bf16(k); k = (k + n) & (N_LEN - 1);
                unsigned hi = cas_bf16(k); k = (k + n) & (N_LEN - 1);
                pk[j] = lo | (hi << 16);
            }
            dst[g] = make_uint4(pk[0], pk[1], pk[2], pk[3]);
        }
    }

    // z regs -> LDS
#pragma unroll
    for (int it = 0; it < 2; ++it) {
        int idx = it * 256 + tid, rr = idx >> 3, c = idx & 7;
        *(uint4*)(zs + rr * PAD + c * 8) = zr[it];
    }
    __syncthreads();

    floatx16 acc[4];
#pragma unroll
    for (int nt = 0; nt < 4; ++nt)
#pragma unroll
        for (int i = 0; i < 16; ++i) acc[nt][i] = 0.f;

#pragma unroll
    for (int ks = 0; ks < 4; ++ks) {
        bf16x8 a = *(const bf16x8*)(zs + (wr * 32 + m) * PAD + ks * 16 + q * 8);
#pragma unroll
        for (int nt = 0; nt < 4; ++nt) {
            bf16x8 b = *(const bf16x8*)(tts + (wn * 128 + nt * 32 + m) * PAD + ks * 16 + q * 8);
            acc[nt] = __builtin_amdgcn_mfma_f32_32x32x16_bf16(a, b, acc[nt], 0, 0, 0);
        }
    }

#pragma unroll
    for (int nt = 0; nt < 4; ++nt) {
#pragma unroll
        for (int r = 0; r < 16; ++r) {
            int rowt = (r & 3) + 8 * (r >> 2) + 4 * q;
            out[(size_t)(row0 + wr * 32 + rowt) * N_LEN + nb0 + wn * 128 + nt * 32 + m]
                = acc[nt][r];
        }
    }
}

// ---------------------------------------------------------------------------
extern "C" void kernel_launch(void* const* d_in, const int* in_sizes, int n_in,
                              void* d_out, int out_size, void* d_ws, size_t ws_size,
                              hipStream_t stream) {
    const float* x  = (const float*)d_in[0];   // (32, 32, 16384)
    const float* w1 = (const float*)d_in[1];   // (32, 32, 64)
    const float* pw = (const float*)d_in[2];   // (32, 32, 64)
    float* out = (float*)d_out;                // (32, 32, 16384)

    const int ntiles = N_LEN / SPLIT / 64;     // 4

    char* p = (char*)d_ws;
    float*          XM  = (float*)p;           p += (size_t)NROWS * NMODES * 4;
    unsigned short* ZB  = (unsigned short*)p;

    // zero the accumulator (graph-capturable memset node)
    hipMemsetAsync(XM, 0, (size_t)NROWS * NMODES * 4, stream);

    gemm1<<<dim3(NROWS / G1_RB, SPLIT), dim3(256), 0, stream>>>(x, XM, ntiles);

    mixk<<<dim3(32, 8), dim3(256), 0, stream>>>(XM, w1, pw, ZB);

    gemm2<<<dim3(NROWS / 64, N_LEN / G2_NB), dim3(256), 0, stream>>>(ZB, out);
}

// Round 3
// 133.085 us; speedup vs baseline: 1.0296x; 1.0296x over previous
//
#include <hip/hip_runtime.h>
#include <math.h>

// Problem constants
#define N_LEN 16384
#define NMODES 64
#define NROWS 1024          // B*C = 32*32
#define PAD 72              // LDS row pitch in bf16 elems (144 B, 16B-aligned)
#define REV_SCALE 6.103515625e-05f   // 1/16384 (exact)

typedef __bf16  bf16x8  __attribute__((ext_vector_type(8)));
typedef float   floatx16 __attribute__((ext_vector_type(16)));

// fp32 -> bf16 round-to-nearest-even (header-independent)
__device__ inline unsigned short f2b(float f) {
    unsigned u = __float_as_uint(f);
    u += 0x7fffu + ((u >> 16) & 1u);
    return (unsigned short)(u >> 16);
}

// cas(2*pi*k/N) rounded to bf16, k in [0, N).  v_sin/v_cos take REVOLUTIONS,
// so the argument needs no range reduction beyond the caller's "& 16383".
__device__ inline unsigned short cas_bf16(unsigned k) {
    float rev = (float)k * REV_SCALE;
#if __has_builtin(__builtin_amdgcn_sinf) && __has_builtin(__builtin_amdgcn_cosf)
    float s = __builtin_amdgcn_sinf(rev);
    float c = __builtin_amdgcn_cosf(rev);
#else
    float s, c;
    sincosf(rev * 6.28318530717958647692f, &s, &c);
#endif
    return f2b(c + s);
}

// ---------------------------------------------------------------------------
// GEMM1: part[s][row][mode] = sum_{n in chunk s} x[row][n] * cas(2pi n m/N)
// MFMA 32x32x16 bf16. Block: 128 rows x 64 modes, 4 waves (wave w = rows
// w*32..+32, both 32-mode N-tiles). Chunk = ntiles*64 n; per 64-n sub-tile:
// stage x (fp32->bf16, reg double-buffered) + GENERATE the 64x64 cas tile
// in LDS (16 cas/thread, v_sin/v_cos — no global table).
// A frag: xs[w*32+(lane&31)][ks*16+(lane>>5)*8]  (16B contiguous)
// B frag: ts[nt*32+(lane&31)][ks*16+(lane>>5)*8]
// D: col(mode)=lane&31, row=(r&3)+8*(r>>2)+4*(lane>>5)   [m74/m101]
// ---------------------------------------------------------------------------
#define G1_RB 128

__global__ __launch_bounds__(256) void gemm1(const float* __restrict__ x,
                                             float* __restrict__ part,
                                             int ntiles) {
    __shared__ unsigned short xs[G1_RB * PAD];   // 18.4 KB
    __shared__ unsigned short ts[64 * PAD];      //  9.2 KB
    const int tid  = threadIdx.x;
    const int lane = tid & 63;
    const int w    = tid >> 6;
    const int q    = lane >> 5;
    const int m    = lane & 31;
    const int row0 = blockIdx.x * G1_RB;
    const int n0   = blockIdx.y * (ntiles * 64);

    // table-gen ownership: this thread fills ts[mrow][nl0 .. nl0+16)
    const int mrow = tid >> 2;
    const int nl0  = (tid & 3) * 16;

    floatx16 acc0, acc1;
#pragma unroll
    for (int i = 0; i < 16; ++i) { acc0[i] = 0.f; acc1[i] = 0.f; }

    float4 xr[8];
    // prologue: load x sub-tile 0 into regs (128 rows x 64 cols fp32)
    {
        const int base = n0;
#pragma unroll
        for (int it = 0; it < 8; ++it) {
            int cid = it * 256 + tid, rr = cid >> 4, cc = (cid & 15) * 4;
            xr[it] = *(const float4*)(x + (size_t)(row0 + rr) * N_LEN + base + cc);
        }
    }

    for (int t = 0; t < ntiles; ++t) {
        __syncthreads();   // previous compute done before LDS overwrite
        // x regs -> LDS (fp32 -> bf16)
#pragma unroll
        for (int it = 0; it < 8; ++it) {
            int cid = it * 256 + tid, rr = cid >> 4, cc = (cid & 15) * 4;
            ushort4 v;
            v.x = f2b(xr[it].x); v.y = f2b(xr[it].y);
            v.z = f2b(xr[it].z); v.w = f2b(xr[it].w);
            *(ushort4*)(xs + rr * PAD + cc) = v;
        }
        // prefetch next x sub-tile (loads stay in flight during table-gen)
        if (t + 1 < ntiles) {
            const int base = n0 + (t + 1) * 64;
#pragma unroll
            for (int it = 0; it < 8; ++it) {
                int cid = it * 256 + tid, rr = cid >> 4, cc = (cid & 15) * 4;
                xr[it] = *(const float4*)(x + (size_t)(row0 + rr) * N_LEN + base + cc);
            }
        }
        // generate cas tile: ts[mrow][nl] = cas(mrow * (n0 + t*64 + nl))
        {
            unsigned nb = (unsigned)(n0 + t * 64 + nl0);
            unsigned k  = ((unsigned)mrow * nb) & (N_LEN - 1);
            unsigned pk[8];
#pragma unroll
            for (int j = 0; j < 8; ++j) {
                unsigned lo = cas_bf16(k); k = (k + mrow) & (N_LEN - 1);
                unsigned hi = cas_bf16(k); k = (k + mrow) & (N_LEN - 1);
                pk[j] = lo | (hi << 16);
            }
            uint4* dst = (uint4*)(ts + mrow * PAD + nl0);
            dst[0] = make_uint4(pk[0], pk[1], pk[2], pk[3]);
            dst[1] = make_uint4(pk[4], pk[5], pk[6], pk[7]);
        }
        __syncthreads();
#pragma unroll
        for (int ks = 0; ks < 4; ++ks) {
            bf16x8 a  = *(const bf16x8*)(xs + (w * 32 + m) * PAD + ks * 16 + q * 8);
            bf16x8 b0 = *(const bf16x8*)(ts + (m)          * PAD + ks * 16 + q * 8);
            bf16x8 b1 = *(const bf16x8*)(ts + (32 + m)     * PAD + ks * 16 + q * 8);
            acc0 = __builtin_amdgcn_mfma_f32_32x32x16_bf16(a, b0, acc0, 0, 0, 0);
            acc1 = __builtin_amdgcn_mfma_f32_32x32x16_bf16(a, b1, acc1, 0, 0, 0);
        }
    }

    // store partials (fp32)
    float* pb = part + ((size_t)blockIdx.y * NROWS + row0 + w * 32) * NMODES;
#pragma unroll
    for (int r = 0; r < 16; ++r) {
        int rowt = (r & 3) + 8 * (r >> 2) + 4 * q;
        pb[rowt * NMODES + m]      = acc0[r];
        pb[rowt * NMODES + 32 + m] = acc1[r];
    }
}

// ---------------------------------------------------------------------------
// Reduce: xm[row][k] = sum_s part[s][row][k]
// 256 blocks (full CU coverage), 1 scalar float per thread, 4 accumulators.
// ---------------------------------------------------------------------------
__global__ __launch_bounds__(256) void reduce_xm(const float* __restrict__ part,
                                                 float* __restrict__ xm, int S) {
    int gid = blockIdx.x * 256 + threadIdx.x;   // 65536 threads, 1 float each
    const float* p = part + gid;
    float a0 = 0.f, a1 = 0.f, a2 = 0.f, a3 = 0.f;
#pragma unroll 4
    for (int s = 0; s < S; s += 4) {
        a0 += p[(size_t)(s + 0) * (NROWS * NMODES)];
        a1 += p[(size_t)(s + 1) * (NROWS * NMODES)];
        a2 += p[(size_t)(s + 2) * (NROWS * NMODES)];
        a3 += p[(size_t)(s + 3) * (NROWS * NMODES)];
    }
    xm[gid] = (a0 + a1) + (a2 + a3);
}

// ---------------------------------------------------------------------------
// Mix: z[b][o][k] = (1/N) * sin(pw[0][o][k]) *
//      sum_i xm[b][i][k]*ye + xm[b][i][kf]*yo,  kf=(64-k)&63.  Output bf16.
// ---------------------------------------------------------------------------
__global__ __launch_bounds__(256) void mixk(const float* __restrict__ xm,
                                            const float* __restrict__ w1,
                                            const float* __restrict__ pw,
                                            unsigned short* __restrict__ zb) {
    int k = threadIdx.x & 63;
    int wave = threadIdx.x >> 6;
    int b = blockIdx.x;
    int o = blockIdx.y * 4 + wave;
    int kf = (NMODES - k) & 63;

    float acc = 0.f;
#pragma unroll 4
    for (int i = 0; i < 32; ++i) {
        float xv  = xm[(size_t)(b * 32 + i) * NMODES + k];
        float xvf = xm[(size_t)(b * 32 + i) * NMODES + kf];
        float w   = w1[(size_t)(i * 32 + o) * NMODES + k];
        float wf  = w1[(size_t)(i * 32 + o) * NMODES + kf];
        acc = fmaf(xv, 0.5f * (w + wf), acc);
        acc = fmaf(xvf, 0.5f * (w - wf), acc);
    }
    const float sc = 1.0f / (float)N_LEN;
    zb[(size_t)(b * 32 + o) * NMODES + k] =
        f2b(acc * sinf(pw[(size_t)o * NMODES + k]) * sc);
}

// ---------------------------------------------------------------------------
// GEMM2: out[row][n] = sum_m z[row][m] * cas(2pi n m/N)   (1/N already in z)
// MFMA 32x32x16 bf16, K=64 = 4 k-steps. Block: 64 rows x 128 n, 4 waves
// (wave w: rows (w&1)*32..+32, n (w>>1)*64..+64 = 2 N-tiles).
// The 128x64 cas tile is GENERATED in LDS: threads 2t,2t+1 own row n=nb0+t,
// 32 modes each (serial cas chain = 32, half of the 256-wide variant).
// LDS 27.6 KB -> 5 blocks/CU residency; grid (16, 128) = 2048 blocks = 8/CU
// spreads table-gen VALU and store bursts across more resident blocks.
// ---------------------------------------------------------------------------
#define G2_NB 128

__global__ __launch_bounds__(256) void gemm2(const unsigned short* __restrict__ zb,
                                             float* __restrict__ out) {
    __shared__ unsigned short tts[G2_NB * PAD];  // 18.4 KB
    __shared__ unsigned short zs[64 * PAD];      //  9.2 KB
    const int tid  = threadIdx.x;
    const int lane = tid & 63;
    const int w    = tid >> 6;
    const int q    = lane >> 5;
    const int m    = lane & 31;
    const int wr   = w & 1;
    const int wn   = w >> 1;
    const int row0 = blockIdx.x * 64;
    const int nb0  = blockIdx.y * G2_NB;

    // stage z tile first (global loads in flight during table-gen VALU)
    uint4 zr[2];
#pragma unroll
    for (int it = 0; it < 2; ++it) {
        int idx = it * 256 + tid, rr = idx >> 3, c = idx & 7;
        zr[it] = *(const uint4*)(zb + (size_t)(row0 + rr) * NMODES + c * 8);
    }

    // generate cas tile: row n = nb0 + (tid>>1); this thread fills cols
    // mm0 .. mm0+32 where mm0 = (tid&1)*32.  k = n*mm mod N, incremental.
    {
        unsigned n   = (unsigned)(nb0 + (tid >> 1));
        unsigned mm0 = (unsigned)((tid & 1) * 32);
        unsigned k   = (n * mm0) & (N_LEN - 1);
        uint4* dst = (uint4*)(tts + (tid >> 1) * PAD + mm0);
#pragma unroll
        for (int g = 0; g < 4; ++g) {
            unsigned pk[4];
#pragma unroll
            for (int j = 0; j < 4; ++j) {
                unsigned lo = cas_bf16(k); k = (k + n) & (N_LEN - 1);
                unsigned hi = cas_bf16(k); k = (k + n) & (N_LEN - 1);
                pk[j] = lo | (hi << 16);
            }
            dst[g] = make_uint4(pk[0], pk[1], pk[2], pk[3]);
        }
    }

    // z regs -> LDS
#pragma unroll
    for (int it = 0; it < 2; ++it) {
        int idx = it * 256 + tid, rr = idx >> 3, c = idx & 7;
        *(uint4*)(zs + rr * PAD + c * 8) = zr[it];
    }
    __syncthreads();

    floatx16 acc[2];
#pragma unroll
    for (int nt = 0; nt < 2; ++nt)
#pragma unroll
        for (int i = 0; i < 16; ++i) acc[nt][i] = 0.f;

#pragma unroll
    for (int ks = 0; ks < 4; ++ks) {
        bf16x8 a = *(const bf16x8*)(zs + (wr * 32 + m) * PAD + ks * 16 + q * 8);
#pragma unroll
        for (int nt = 0; nt < 2; ++nt) {
            bf16x8 b = *(const bf16x8*)(tts + (wn * 64 + nt * 32 + m) * PAD + ks * 16 + q * 8);
            acc[nt] = __builtin_amdgcn_mfma_f32_32x32x16_bf16(a, b, acc[nt], 0, 0, 0);
        }
    }

#pragma unroll
    for (int nt = 0; nt < 2; ++nt) {
#pragma unroll
        for (int r = 0; r < 16; ++r) {
            int rowt = (r & 3) + 8 * (r >> 2) + 4 * q;
            out[(size_t)(row0 + wr * 32 + rowt) * N_LEN + nb0 + wn * 64 + nt * 32 + m]
                = acc[nt][r];
        }
    }
}

// ---------------------------------------------------------------------------
extern "C" void kernel_launch(void* const* d_in, const int* in_sizes, int n_in,
                              void* d_out, int out_size, void* d_ws, size_t ws_size,
                              hipStream_t stream) {
    const float* x  = (const float*)d_in[0];   // (32, 32, 16384)
    const float* w1 = (const float*)d_in[1];   // (32, 32, 64)
    const float* pw = (const float*)d_in[2];   // (32, 32, 64)
    float* out = (float*)d_out;                // (32, 32, 16384)

    // split-K factor by workspace (constant across calls)
    int S = 64;
    while (S > 8) {
        size_t need = (size_t)S * NROWS * NMODES * 4u               // partials
                    + (size_t)NROWS * NMODES * 4u                   // xm
                    + (size_t)NROWS * NMODES * 2u;                  // zb
        if (need <= ws_size) break;
        S >>= 1;
    }
    const int ntiles = N_LEN / S / 64;

    char* p = (char*)d_ws;
    float*          P   = (float*)p;                    p += (size_t)S * NROWS * NMODES * 4;
    float*          XM  = (float*)p;                    p += (size_t)NROWS * NMODES * 4;
    unsigned short* ZB  = (unsigned short*)p;

    gemm1<<<dim3(NROWS / G1_RB, S), dim3(256), 0, stream>>>(x, P, ntiles);

    reduce_xm<<<dim3(NROWS * NMODES / 256), dim3(256), 0, stream>>>(P, XM, S);

    mixk<<<dim3(32, 8), dim3(256), 0, stream>>>(XM, w1, pw, ZB);

    gemm2<<<dim3(NROWS / 64, N_LEN / G2_NB), dim3(256), 0, stream>>>(ZB, out);
}